// Round 13
// baseline (429.035 us; speedup 1.0000x reference)
//
#include <hip/hip_runtime.h>
#include <hip/hip_bf16.h>

// ---------- types ----------
typedef __attribute__((ext_vector_type(8))) __bf16 bf16x8;
typedef __attribute__((ext_vector_type(4))) float f32x4;
typedef __attribute__((ext_vector_type(4))) unsigned short us4;

__device__ __forceinline__ unsigned short f2bf(float f) {
    unsigned u = __float_as_uint(f);
    u += 0x7FFFu + ((u >> 16) & 1u);   // RNE
    return (unsigned short)(u >> 16);
}

__device__ __forceinline__ void gload16(const void* g, void* l) {
    __builtin_amdgcn_global_load_lds(
        (const __attribute__((address_space(1))) unsigned int*)g,
        (__attribute__((address_space(3))) unsigned int*)l,
        16, 0, 0);
}

// ---------- kernel 1: fp32 -> bf16 (x) ----------
__global__ void cvt_f32_bf16(const float* __restrict__ in, unsigned short* __restrict__ out, int n4) {
    int i = blockIdx.x * blockDim.x + threadIdx.x;
    if (i >= n4) return;
    float4 v = ((const float4*)in)[i];
    us4 r = { f2bf(v.x), f2bf(v.y), f2bf(v.z), f2bf(v.w) };
    ((us4*)out)[i] = r;
}

// ---------- kernel 2: transpose + convert: in[R][C] f32 -> out[C][R] bf16 ----------
__global__ void tcvt(const float* __restrict__ in, unsigned short* __restrict__ out, int R, int C) {
    __shared__ float tile[32][33];
    int tx = threadIdx.x & 31, ty = threadIdx.x >> 5;  // 256 threads
    int c0 = blockIdx.x * 32, r0 = blockIdx.y * 32;
    #pragma unroll
    for (int i = 0; i < 32; i += 8)
        tile[ty + i][tx] = in[(size_t)(r0 + ty + i) * C + c0 + tx];
    __syncthreads();
    #pragma unroll
    for (int i = 0; i < 32; i += 8)
        out[(size_t)(c0 + ty + i) * R + r0 + tx] = f2bf(tile[tx][ty + i]);
}

// ---------- 256xBN GEMM, 16 waves (1024 thr), BK=32, dbuf, 2+ blocks/CU ----------
// Occupancy lever: BK=32 halves LDS to 64KB (BN=256) / 48KB (BN=128) -> 2-3 blocks/CU;
// cross-block overlap hides the per-iter chain stall (blocks don't share barriers).
// LDS layout: 128B rows pair two m-rows; slot s of lds-row r holds (half,kgroup) with
// half*4+kg = s ^ (r&7). Read slot = ((m&1)*4+hig) ^ ((m>>1)&7): 64 lanes cover each
// 128B row exactly once -> conflict-free (b128 8-cyc floor).
#define MFW(af, bf, fi, ni) acc[fi][ni] = __builtin_amdgcn_mfma_f32_16x16x32_bf16(af, bf, acc[fi][ni], 0, 0, 0)

template <int MODE, int BN>
__global__ __launch_bounds__(1024) void gemmw(
    const unsigned short* __restrict__ A, const unsigned short* __restrict__ Bt,
    int M, int N, int K, float* __restrict__ Cf,
    unsigned short* __restrict__ qp, unsigned short* __restrict__ kp,
    unsigned short* __restrict__ vTp,
    const float* __restrict__ ropeC, const float* __restrict__ ropeS,
    int cby, int cbx)
{
    constexpr int ASZ = 16384;                 // A region: 128 lds-rows x 128B
    constexpr int BSZ = (BN >> 1) * 128;       // B region
    constexpr int BUF = ASZ + BSZ;
    constexpr int FN = BN / 64;
    __shared__ char lds[2 * BUF];
    const int tid = threadIdx.x;
    const int lane = tid & 63, wid = tid >> 6;      // wid 0..15
    const int ln15 = lane & 15, hig = lane >> 4;
    const int wrow = wid >> 2, wcol = wid & 3;      // 4x4 wave grid

    // 2D-chunk XCD swizzle: 8 chunks of (cby x cbx) blocks
    int nwg = gridDim.x * gridDim.y;
    int flat = blockIdx.y * gridDim.x + blockIdx.x;
    int bx, by;
    if ((nwg & 7) == 0) {
        int c = flat & 7, local = flat >> 3;
        int chunkCols = gridDim.x / cbx;
        by = (c / chunkCols) * cby + local / cbx;
        bx = (c % chunkCols) * cbx + local % cbx;
    } else {
        bx = flat % gridDim.x; by = flat / gridDim.x;
    }
    const int mbase = by * 256, nbase = bx * BN;
    const size_t Kb = (size_t)K * 2;

    const char* Ag = (const char*)A + (size_t)mbase * Kb;
    const char* Bg = (const char*)Bt + (size_t)nbase * Kb;
    char* L = (char*)lds;

    // staging: A slot (r=tid>>3, s=tid&7); content c = s ^ (r&7) -> row 2r+(c>>2), kg=c&3
    const int ar = tid >> 3, as_ = tid & 7;
    const int ac = as_ ^ (ar & 7);
    const size_t aSrc = (size_t)(2 * ar + (ac >> 2)) * Kb + (ac & 3) * 16;
    const int aDst = tid * 16;
    // B staging (BN=128: threads < 512 only)
    const int bvalid = (BN == 256) || (tid < 512);
    const int br = tid >> 3, bs_ = tid & 7;
    const int bc = bs_ ^ (br & 7);
    const size_t bSrc = (size_t)(2 * br + (bc >> 2)) * Kb + (bc & 3) * 16;
    const int bDst = ASZ + tid * 16;

    // read offsets
    const int slotRW = (((ln15 & 1) << 2) | hig) ^ ((ln15 >> 1) & 7);
    const int aOff = (wrow * 32 + (ln15 >> 1)) * 128 + slotRW * 16;               // + fm*1024
    const int bOff = ASZ + ((BN == 256 ? wcol * 32 : wcol * 16) + (ln15 >> 1)) * 128 + slotRW * 16; // + fn*1024

    f32x4 acc[4][FN] = {};
    const int T = K >> 5;

    {   // prologue: stage tile 0
        char* bb = L;
        gload16(Ag + aSrc, bb + aDst);
        if (bvalid) gload16(Bg + bSrc, bb + bDst);
    }
    asm volatile("s_waitcnt vmcnt(0)" ::: "memory");
    __builtin_amdgcn_s_barrier();
    asm volatile("" ::: "memory");

    for (int t = 0; t < T; t++) {
        char* bb = L + (t & 1) * BUF;
        if (t + 1 < T) {
            char* nb = L + ((t + 1) & 1) * BUF;
            size_t ko = (size_t)(t + 1) * 64;
            gload16(Ag + aSrc + ko, nb + aDst);
            if (bvalid) gload16(Bg + bSrc + ko, nb + bDst);
        }
        bf16x8 av[4], bv[FN];
        #pragma unroll
        for (int i = 0; i < 4; i++) av[i] = *(const bf16x8*)(bb + aOff + i * 1024);
        #pragma unroll
        for (int j = 0; j < FN; j++) bv[j] = *(const bf16x8*)(bb + bOff + j * 1024);
        #pragma unroll
        for (int i = 0; i < 4; i++)
            #pragma unroll
            for (int j = 0; j < FN; j++)
                MFW(av[i], bv[j], i, j);

        if (t + 1 < T) {
            asm volatile("s_waitcnt vmcnt(0)" ::: "memory");   // next tile landed
            __builtin_amdgcn_s_barrier();                      // all waves done with bb
            asm volatile("" ::: "memory");
        }
    }

    if (MODE == 0) {
        #pragma unroll
        for (int fm = 0; fm < 4; fm++)
            #pragma unroll
            for (int fn = 0; fn < FN; fn++)
                #pragma unroll
                for (int j = 0; j < 4; j++) {
                    int m = mbase + wrow * 64 + fm * 16 + hig * 4 + j;
                    int col = nbase + wcol * (BN / 4) + fn * 16 + ln15;
                    Cf[(size_t)m * N + col] = acc[fm][fn][j];
                }
    } else {
        const int colb = nbase + wcol * 64;
        const int sec = colb >> 11;               // 0=q, 1=k, 2=v
        if (sec < 2) {
            unsigned short* dst = (sec == 0) ? qp : kp;
            const float scale = (sec == 0) ? 0.08838834764831845f : 1.0f;
            #pragma unroll
            for (int fm = 0; fm < 4; fm++)
                #pragma unroll
                for (int fn = 0; fn < FN; fn++) {
                    int within = (colb & 2047) + fn * 16 + ln15;
                    int h = within >> 7, d = within & 127, pidx = d >> 1;
                    #pragma unroll
                    for (int j = 0; j < 4; j++) {
                        int m = mbase + wrow * 64 + fm * 16 + hig * 4 + j;
                        int b = m >> 11, tq = m & 2047;
                        float v = acc[fm][fn][j];
                        float pv = __shfl_xor(v, 1);
                        float c = ropeC[tq * 64 + pidx], s = ropeS[tq * 64 + pidx];
                        float o = (d & 1) ? fmaf(pv, s, v * c) : fmaf(-pv, s, v * c);
                        o *= scale;
                        dst[((size_t)((b << 4) + h) * 2048 + tq) * 128 + d] = f2bf(o);
                    }
                }
        } else {
            #pragma unroll
            for (int fm = 0; fm < 4; fm++)
                #pragma unroll
                for (int fn = 0; fn < FN; fn++) {
                    int within = (colb & 2047) + fn * 16 + ln15;
                    int h = within >> 7, d = within & 127;
                    int m0 = mbase + wrow * 64 + fm * 16 + hig * 4;
                    int b = m0 >> 11, t0 = m0 & 2047;
                    us4 pk = { f2bf(acc[fm][fn][0]), f2bf(acc[fm][fn][1]),
                               f2bf(acc[fm][fn][2]), f2bf(acc[fm][fn][3]) };
                    *(us4*)(vTp + ((size_t)((b << 4) + h) * 128 + d) * 2048 + t0) = pk;
                }
        }
    }
}

// ---------- flash attention (R10 proven): causal, swapped QK^T, KVBLK=64, dbuf, counted vmcnt ----------
// grid: (64, 8)  x = bh (XCD locality), y = q-pair.  q,k: [BH][T][D] (q pre-scaled); vT: [BH][D][T]
__global__ __launch_bounds__(256, 2) void attn_fwd(
    const unsigned short* __restrict__ q, const unsigned short* __restrict__ k,
    const unsigned short* __restrict__ vT, unsigned short* __restrict__ outp)
{
    __shared__ unsigned short lK[2][64 * 128];   // 2 x 16 KB, [kv][d], XOR-swizzled rows (256B)
    __shared__ unsigned short lV[2][128 * 64];   // 2 x 16 KB, [d][kv], XOR-swizzled rows (128B)
    __shared__ unsigned short lP[4 * 32 * 64];   // 16 KB, per-wave
    const int tid = threadIdx.x;
    const int lane = tid & 63, wid = tid >> 6;
    const int ln15 = lane & 15, hig = lane >> 4, hi8 = hig * 8;
    const int bh = blockIdx.x;

    const char* qg = (const char*)(q + (size_t)bh * 2048 * 128);
    const char* kg = (const char*)(k + (size_t)bh * 2048 * 128);
    const char* vg = (const char*)(vT + (size_t)bh * 128 * 2048);
    char* lKc = (char*)&lK[0][0];
    char* lVc = (char*)&lV[0][0];
    char* lPc = (char*)lP + wid * (32 * 64 * 2);
    const int b = bh >> 4, h = bh & 15;

    for (int rep = 0; rep < 2; rep++) {
        const int qt = rep == 0 ? (int)blockIdx.y : 15 - (int)blockIdx.y;
        const int qbase = qt * 128;
        const int qw = qbase + wid * 32;

        bf16x8 qf[2][4];
        #pragma unroll
        for (int mt = 0; mt < 2; mt++)
            #pragma unroll
            for (int ks = 0; ks < 4; ks++)
                qf[mt][ks] = *(const bf16x8*)(qg + ((size_t)(qw + mt * 16 + ln15) * 128 + ks * 32 + hi8) * 2);

        f32x4 o[2][8] = {};
        float mreg[2] = { -1e30f, -1e30f };
        float lreg[2] = { 0.f, 0.f };

        auto stageKV = [&](int bf, int kv0) {
            #pragma unroll
            for (int i = 0; i < 4; i++) {
                int slot = tid + i * 256;
                int row = slot >> 4, c = (slot & 15) * 16;
                gload16(kg + (size_t)(kv0 + row) * 256 + (c ^ ((row & 7) << 4)),
                        lKc + bf * 16384 + slot * 16);
            }
            #pragma unroll
            for (int i = 0; i < 4; i++) {
                int slot = tid + i * 256;
                int d = slot >> 3, c = (slot & 7) * 16;
                gload16(vg + (size_t)d * 4096 + (size_t)kv0 * 2 + (c ^ ((d & 7) << 4)),
                        lVc + bf * 16384 + slot * 16);
            }
        };

        const int ntiles = (qbase >> 6) + 2;   // >= 2 always
        stageKV(0, 0);
        if (ntiles > 1) stageKV(1, 64);

        for (int it = 0; it < ntiles; it++) {
            const int kv0 = it * 64;
            const int buf = it & 1;
            if (it + 1 < ntiles) asm volatile("s_waitcnt vmcnt(8)" ::: "memory");
            else                 asm volatile("s_waitcnt vmcnt(0)" ::: "memory");
            __builtin_amdgcn_s_barrier();

            if (kv0 <= qw + 31) {   // wave-active (causal range)
                const char* lKb = lKc + buf * 16384;
                const char* lVb = lVc + buf * 16384;

                f32x4 s[2][4] = {};
                #pragma unroll
                for (int ks = 0; ks < 4; ks++) {
                    bf16x8 kf[4];
                    #pragma unroll
                    for (int nt = 0; nt < 4; nt++) {
                        int row = nt * 16 + ln15;
                        kf[nt] = *(const bf16x8*)(lKb + row * 256 + (((ks * 32 + hi8) * 2) ^ ((row & 7) << 4)));
                    }
                    __builtin_amdgcn_s_setprio(1);
                    #pragma unroll
                    for (int mt = 0; mt < 2; mt++)
                        #pragma unroll
                        for (int nt = 0; nt < 4; nt++)
                            s[mt][nt] = __builtin_amdgcn_mfma_f32_16x16x32_bf16(kf[nt], qf[mt][ks], s[mt][nt], 0, 0, 0);
                    __builtin_amdgcn_s_setprio(0);
                }

                if (kv0 + 63 > qw) {  // diagonal tile: mask kv > q
                    #pragma unroll
                    for (int mt = 0; mt < 2; mt++) {
                        int qi = qw + mt * 16 + ln15;
                        #pragma unroll
                        for (int nt = 0; nt < 4; nt++)
                            #pragma unroll
                            for (int j = 0; j < 4; j++) {
                                int kvi = kv0 + nt * 16 + 4 * hig + j;
                                if (kvi > qi) s[mt][nt][j] = -1e30f;
                            }
                    }
                }

                float vmax[2];
                #pragma unroll
                for (int mt = 0; mt < 2; mt++) {
                    float v = fmaxf(fmaxf(s[mt][0][0], s[mt][0][1]), fmaxf(s[mt][0][2], s[mt][0][3]));
                    #pragma unroll
                    for (int nt = 1; nt < 4; nt++)
                        v = fmaxf(v, fmaxf(fmaxf(s[mt][nt][0], s[mt][nt][1]), fmaxf(s[mt][nt][2], s[mt][nt][3])));
                    v = fmaxf(v, __shfl_xor(v, 16));
                    v = fmaxf(v, __shfl_xor(v, 32));
                    vmax[mt] = v;
                }
                bool grow = (vmax[0] > mreg[0] + 8.0f) || (vmax[1] > mreg[1] + 8.0f);
                if (__any(grow)) {
                    float sc[2];
                    #pragma unroll
                    for (int mt = 0; mt < 2; mt++) {
                        float mn = fmaxf(mreg[mt], vmax[mt]);
                        sc[mt] = __expf(mreg[mt] - mn);
                        mreg[mt] = mn;
                        lreg[mt] *= sc[mt];
                    }
                    #pragma unroll
                    for (int mt = 0; mt < 2; mt++)
                        #pragma unroll
                        for (int j = 0; j < 4; j++) {
                            float scj = __shfl(sc[mt], 4 * hig + j);
                            #pragma unroll
                            for (int ntd = 0; ntd < 8; ntd++) o[mt][ntd][j] *= scj;
                        }
                }
                #pragma unroll
                for (int mt = 0; mt < 2; mt++) {
                    float rs = 0.f;
                    #pragma unroll
                    for (int nt = 0; nt < 4; nt++)
                        #pragma unroll
                        for (int j = 0; j < 4; j++) {
                            float p = __expf(s[mt][nt][j] - mreg[mt]);
                            s[mt][nt][j] = p;
                            rs += p;
                        }
                    rs += __shfl_xor(rs, 16);
                    rs += __shfl_xor(rs, 32);
                    lreg[mt] += rs;
                }

                #pragma unroll
                for (int mt = 0; mt < 2; mt++) {
                    int rr = mt * 16 + ln15;
                    int rx = (rr & 7) << 4;
                    #pragma unroll
                    for (int nt = 0; nt < 4; nt++) {
                        us4 pk = { f2bf(s[mt][nt][0]), f2bf(s[mt][nt][1]),
                                   f2bf(s[mt][nt][2]), f2bf(s[mt][nt][3]) };
                        int addr = rr * 128 + ((nt * 32 + hig * 8) ^ rx);
                        *(us4*)(lPc + addr) = pk;
                    }
                }

                #pragma unroll
                for (int ks2 = 0; ks2 < 2; ks2++) {
                    bf16x8 pf[2];
                    #pragma unroll
                    for (int mt = 0; mt < 2; mt++) {
                        int row = mt * 16 + ln15;
                        pf[mt] = *(const bf16x8*)(lPc + row * 128 + (((ks2 * 32 + hi8) * 2) ^ ((row & 7) << 4)));
                    }
                    #pragma unroll
                    for (int ntd = 0; ntd < 8; ntd++) {
                        int drow = ntd * 16 + ln15;
                        bf16x8 vf = *(const bf16x8*)(lVb + drow * 128 + (((ks2 * 32 + hi8) * 2) ^ ((drow & 7) << 4)));
                        __builtin_amdgcn_s_setprio(1);
                        #pragma unroll
                        for (int mt = 0; mt < 2; mt++)
                            o[mt][ntd] = __builtin_amdgcn_mfma_f32_16x16x32_bf16(pf[mt], vf, o[mt][ntd], 0, 0, 0);
                        __builtin_amdgcn_s_setprio(0);
                    }
                }
            }

            __builtin_amdgcn_s_barrier();
            if (it + 2 < ntiles) stageKV(buf, kv0 + 128);
        }

        #pragma unroll
        for (int mt = 0; mt < 2; mt++)
            #pragma unroll
            for (int j = 0; j < 4; j++) {
                float inv = 1.0f / __shfl(lreg[mt], 4 * hig + j);
                int t = qw + mt * 16 + hig * 4 + j;
                #pragma unroll
                for (int ntd = 0; ntd < 8; ntd++) {
                    int d = ntd * 16 + ln15;
                    outp[((size_t)b * 2048 + t) * 2048 + h * 128 + d] = f2bf(o[mt][ntd][j] * inv);
                }
            }
    }
}

// ---------- launcher ----------
extern "C" void kernel_launch(void* const* d_in, const int* in_sizes, int n_in,
                              void* d_out, int out_size, void* d_ws, size_t ws_size,
                              hipStream_t stream) {
    const float* x     = (const float*)d_in[0];
    const float* wqkv  = (const float*)d_in[1];
    const float* wo    = (const float*)d_in[2];
    const float* ropeC = (const float*)d_in[3];
    const float* ropeS = (const float*)d_in[4];
    float* out = (float*)d_out;
    char* ws = (char*)d_ws;
    const size_t MB = 1024 * 1024;
    unsigned short* xb    = (unsigned short*)(ws);                  // 32 MB
    unsigned short* wqkvT = (unsigned short*)(ws + 32 * MB);        // 24 MB
    unsigned short* woT   = (unsigned short*)(ws + 56 * MB);        // 8 MB
    unsigned short* qb    = (unsigned short*)(ws + 64 * MB);        // 32 MB
    unsigned short* kb    = (unsigned short*)(ws + 96 * MB);        // 32 MB
    unsigned short* vTb   = (unsigned short*)(ws + 128 * MB);       // 32 MB
    unsigned short* attnb = (unsigned short*)(ws + 160 * MB);       // 32 MB

    cvt_f32_bf16<<<16384, 256, 0, stream>>>(x, xb, 4194304);
    tcvt<<<dim3(192, 64), 256, 0, stream>>>(wqkv, wqkvT, 2048, 6144);
    tcvt<<<dim3(64, 64), 256, 0, stream>>>(wo, woT, 2048, 2048);
    gemmw<1, 256><<<dim3(24, 32), 1024, 0, stream>>>(xb, wqkvT, 8192, 6144, 2048,
                                                     nullptr, qb, kb, vTb, ropeC, ropeS, 8, 12);
    attn_fwd<<<dim3(64, 8), 256, 0, stream>>>(qb, kb, vTb, attnb);
    gemmw<0, 128><<<dim3(16, 32), 1024, 0, stream>>>(attnb, woT, 8192, 2048, 2048,
                                                     out, nullptr, nullptr, nullptr, nullptr, nullptr, 8, 8);
}

// Round 14
// 402.322 us; speedup vs baseline: 1.0664x; 1.0664x over previous
//
#include <hip/hip_runtime.h>
#include <hip/hip_bf16.h>

// ---------- types ----------
typedef __attribute__((ext_vector_type(8))) __bf16 bf16x8;
typedef __attribute__((ext_vector_type(4))) float f32x4;
typedef __attribute__((ext_vector_type(4))) unsigned short us4;

__device__ __forceinline__ unsigned short f2bf(float f) {
    unsigned u = __float_as_uint(f);
    u += 0x7FFFu + ((u >> 16) & 1u);   // RNE
    return (unsigned short)(u >> 16);
}

__device__ __forceinline__ void gload16(const void* g, void* l) {
    __builtin_amdgcn_global_load_lds(
        (const __attribute__((address_space(1))) unsigned int*)g,
        (__attribute__((address_space(3))) unsigned int*)l,
        16, 0, 0);
}

// ---------- kernel 1: fp32 -> bf16 (x) ----------
__global__ void cvt_f32_bf16(const float* __restrict__ in, unsigned short* __restrict__ out, int n4) {
    int i = blockIdx.x * blockDim.x + threadIdx.x;
    if (i >= n4) return;
    float4 v = ((const float4*)in)[i];
    us4 r = { f2bf(v.x), f2bf(v.y), f2bf(v.z), f2bf(v.w) };
    ((us4*)out)[i] = r;
}

// ---------- kernel 2: transpose + convert: in[R][C] f32 -> out[C][R] bf16 ----------
__global__ void tcvt(const float* __restrict__ in, unsigned short* __restrict__ out, int R, int C) {
    __shared__ float tile[32][33];
    int tx = threadIdx.x & 31, ty = threadIdx.x >> 5;  // 256 threads
    int c0 = blockIdx.x * 32, r0 = blockIdx.y * 32;
    #pragma unroll
    for (int i = 0; i < 32; i += 8)
        tile[ty + i][tx] = in[(size_t)(r0 + ty + i) * C + c0 + tx];
    __syncthreads();
    #pragma unroll
    for (int i = 0; i < 32; i += 8)
        out[(size_t)(c0 + ty + i) * R + r0 + tx] = f2bf(tile[tx][ty + i]);
}

// ---------- 256x256 GEMM, 16 waves (1024 thr), per-wave 64x64, BK=64, dbuf (R8/R10 proven) ----------
// LDS per buf (64 KB): A = 256 rows x 128B at [0,32K), B at [32K,64K). Buf stride 64K.
// Row layout: 8 x 16B slots; slot h of row r holds k-group h ^ (r&7)  (2-way read conflicts = free).
// TLP design: 4 waves/SIMD (VGPR 56); no setprio (flat on lockstep GEMM, m190/R10).
#define MFW(af, bf, fi, ni) acc[fi][ni] = __builtin_amdgcn_mfma_f32_16x16x32_bf16(af, bf, acc[fi][ni], 0, 0, 0)
#define MFMA16W() do { \
    MFW(a0,b0,0,0); MFW(a0,b1,0,1); MFW(a0,b2,0,2); MFW(a0,b3,0,3); \
    MFW(a1,b0,1,0); MFW(a1,b1,1,1); MFW(a1,b2,1,2); MFW(a1,b3,1,3); \
    MFW(a2,b0,2,0); MFW(a2,b1,2,1); MFW(a2,b2,2,2); MFW(a2,b3,2,3); \
    MFW(a3,b0,3,0); MFW(a3,b1,3,1); MFW(a3,b2,3,2); MFW(a3,b3,3,3); } while(0)
#define STGW(kt, bufo) do { \
    size_t ko = (size_t)(kt) * 128; \
    char* bb = L + (bufo); \
    gload16(Ag + sR + ko, bb + dstA); \
    gload16(Ag + sR2 + ko, bb + dstA + 16384); \
    gload16(Bg + sR + ko, bb + 32768 + dstA); \
    gload16(Bg + sR2 + ko, bb + 32768 + dstA + 16384); } while (0)

template <int MODE>
__global__ __launch_bounds__(1024, 4) void gemmw(
    const unsigned short* __restrict__ A, const unsigned short* __restrict__ Bt,
    int M, int N, int K, float* __restrict__ Cf,
    unsigned short* __restrict__ qp, unsigned short* __restrict__ kp,
    unsigned short* __restrict__ vTp,
    const float* __restrict__ ropeC, const float* __restrict__ ropeS,
    int cby, int cbx)
{
    __shared__ unsigned short lds[2][32768];   // 128 KB
    const int tid = threadIdx.x;
    const int lane = tid & 63, wid = tid >> 6;      // wid 0..15
    const int ln15 = lane & 15, hig = lane >> 4;
    const int wrow = wid >> 2, wcol = wid & 3;      // 4x4 wave grid, 64x64 each

    int nwg = gridDim.x * gridDim.y;
    int flat = blockIdx.y * gridDim.x + blockIdx.x;
    int bx, by;
    if ((nwg & 7) == 0) {
        int c = flat & 7, local = flat >> 3;
        int chunkCols = gridDim.x / cbx;
        by = (c / chunkCols) * cby + local / cbx;
        bx = (c % chunkCols) * cbx + local % cbx;
    } else {
        bx = flat % gridDim.x; by = flat / gridDim.x;
    }
    const int mbase = by * 256, nbase = bx * 256;
    const size_t Kb = (size_t)K * 2;

    const char* Ag = (const char*)A + (size_t)mbase * Kb;
    const char* Bg = (const char*)Bt + (size_t)nbase * Kb;
    char* L = (char*)&lds[0][0];

    const int srow = tid >> 3;
    const int gs = (tid & 7) ^ (srow & 7);
    const size_t sR = (size_t)srow * Kb + gs * 16;
    const size_t sR2 = sR + (size_t)128 * Kb;
    const int dstA = tid * 16;

    const int aBase = (wrow * 64 + ln15) * 128;
    const int bBase = 32768 + (wcol * 64 + ln15) * 128;
    const int sl0 = (hig ^ (ln15 & 7)) * 16;
    const int sl1 = ((4 + hig) ^ (ln15 & 7)) * 16;

    f32x4 acc[4][4] = {};
    const int T = K >> 6;

    STGW(0, 0);
    asm volatile("s_waitcnt vmcnt(0)" ::: "memory");
    __builtin_amdgcn_s_barrier();
    asm volatile("" ::: "memory");

    for (int t = 0; t < T; t++) {
        char* bb = L + (t & 1) * 65536;
        if (t + 1 < T) STGW(t + 1, ((t + 1) & 1) * 65536);
        bf16x8 a0, a1, a2, a3, b0, b1, b2, b3;
        // kk0
        a0 = *(const bf16x8*)(bb + aBase + 0 * 2048 + sl0);
        a1 = *(const bf16x8*)(bb + aBase + 1 * 2048 + sl0);
        a2 = *(const bf16x8*)(bb + aBase + 2 * 2048 + sl0);
        a3 = *(const bf16x8*)(bb + aBase + 3 * 2048 + sl0);
        b0 = *(const bf16x8*)(bb + bBase + 0 * 2048 + sl0);
        b1 = *(const bf16x8*)(bb + bBase + 1 * 2048 + sl0);
        b2 = *(const bf16x8*)(bb + bBase + 2 * 2048 + sl0);
        b3 = *(const bf16x8*)(bb + bBase + 3 * 2048 + sl0);
        MFMA16W();
        // kk1
        a0 = *(const bf16x8*)(bb + aBase + 0 * 2048 + sl1);
        a1 = *(const bf16x8*)(bb + aBase + 1 * 2048 + sl1);
        a2 = *(const bf16x8*)(bb + aBase + 2 * 2048 + sl1);
        a3 = *(const bf16x8*)(bb + aBase + 3 * 2048 + sl1);
        b0 = *(const bf16x8*)(bb + bBase + 0 * 2048 + sl1);
        b1 = *(const bf16x8*)(bb + bBase + 1 * 2048 + sl1);
        b2 = *(const bf16x8*)(bb + bBase + 2 * 2048 + sl1);
        b3 = *(const bf16x8*)(bb + bBase + 3 * 2048 + sl1);
        MFMA16W();

        if (t + 1 < T) {
            asm volatile("s_waitcnt vmcnt(0)" ::: "memory");
            __builtin_amdgcn_s_barrier();
            asm volatile("" ::: "memory");
        }
    }

    if (MODE == 0) {
        #pragma unroll
        for (int fm = 0; fm < 4; fm++)
            #pragma unroll
            for (int fn = 0; fn < 4; fn++)
                #pragma unroll
                for (int j = 0; j < 4; j++) {
                    int m = mbase + wrow * 64 + fm * 16 + hig * 4 + j;
                    int col = nbase + wcol * 64 + fn * 16 + ln15;
                    Cf[(size_t)m * N + col] = acc[fm][fn][j];
                }
    } else {
        const int colb = nbase + wcol * 64;
        const int sec = colb >> 11;               // 0=q, 1=k, 2=v
        if (sec < 2) {
            unsigned short* dst = (sec == 0) ? qp : kp;
            const float scale = (sec == 0) ? 0.08838834764831845f : 1.0f;
            #pragma unroll
            for (int fm = 0; fm < 4; fm++)
                #pragma unroll
                for (int fn = 0; fn < 4; fn++) {
                    int within = (colb & 2047) + fn * 16 + ln15;
                    int h = within >> 7, d = within & 127, pidx = d >> 1;
                    #pragma unroll
                    for (int j = 0; j < 4; j++) {
                        int m = mbase + wrow * 64 + fm * 16 + hig * 4 + j;
                        int b = m >> 11, tq = m & 2047;
                        float v = acc[fm][fn][j];
                        float pv = __shfl_xor(v, 1);
                        float c = ropeC[tq * 64 + pidx], s = ropeS[tq * 64 + pidx];
                        float o = (d & 1) ? fmaf(pv, s, v * c) : fmaf(-pv, s, v * c);
                        o *= scale;
                        dst[((size_t)((b << 4) + h) * 2048 + tq) * 128 + d] = f2bf(o);
                    }
                }
        } else {
            #pragma unroll
            for (int fm = 0; fm < 4; fm++)
                #pragma unroll
                for (int fn = 0; fn < 4; fn++) {
                    int within = (colb & 2047) + fn * 16 + ln15;
                    int h = within >> 7, d = within & 127;
                    int m0 = mbase + wrow * 64 + fm * 16 + hig * 4;
                    int b = m0 >> 11, t0 = m0 & 2047;
                    us4 pk = { f2bf(acc[fm][fn][0]), f2bf(acc[fm][fn][1]),
                               f2bf(acc[fm][fn][2]), f2bf(acc[fm][fn][3]) };
                    *(us4*)(vTp + ((size_t)((b << 4) + h) * 128 + d) * 2048 + t0) = pk;
                }
        }
    }
}

// ---------- flash attention (R10 proven): causal, swapped QK^T, KVBLK=64, dbuf, counted vmcnt ----------
// grid: (64, 8)  x = bh (XCD locality), y = q-pair.  q,k: [BH][T][D] (q pre-scaled); vT: [BH][D][T]
__global__ __launch_bounds__(256, 2) void attn_fwd(
    const unsigned short* __restrict__ q, const unsigned short* __restrict__ k,
    const unsigned short* __restrict__ vT, unsigned short* __restrict__ outp)
{
    __shared__ unsigned short lK[2][64 * 128];   // 2 x 16 KB, [kv][d], XOR-swizzled rows (256B)
    __shared__ unsigned short lV[2][128 * 64];   // 2 x 16 KB, [d][kv], XOR-swizzled rows (128B)
    __shared__ unsigned short lP[4 * 32 * 64];   // 16 KB, per-wave
    const int tid = threadIdx.x;
    const int lane = tid & 63, wid = tid >> 6;
    const int ln15 = lane & 15, hig = lane >> 4, hi8 = hig * 8;
    const int bh = blockIdx.x;

    const char* qg = (const char*)(q + (size_t)bh * 2048 * 128);
    const char* kg = (const char*)(k + (size_t)bh * 2048 * 128);
    const char* vg = (const char*)(vT + (size_t)bh * 128 * 2048);
    char* lKc = (char*)&lK[0][0];
    char* lVc = (char*)&lV[0][0];
    char* lPc = (char*)lP + wid * (32 * 64 * 2);
    const int b = bh >> 4, h = bh & 15;

    for (int rep = 0; rep < 2; rep++) {
        const int qt = rep == 0 ? (int)blockIdx.y : 15 - (int)blockIdx.y;
        const int qbase = qt * 128;
        const int qw = qbase + wid * 32;

        bf16x8 qf[2][4];
        #pragma unroll
        for (int mt = 0; mt < 2; mt++)
            #pragma unroll
            for (int ks = 0; ks < 4; ks++)
                qf[mt][ks] = *(const bf16x8*)(qg + ((size_t)(qw + mt * 16 + ln15) * 128 + ks * 32 + hi8) * 2);

        f32x4 o[2][8] = {};
        float mreg[2] = { -1e30f, -1e30f };
        float lreg[2] = { 0.f, 0.f };

        auto stageKV = [&](int bf, int kv0) {
            #pragma unroll
            for (int i = 0; i < 4; i++) {
                int slot = tid + i * 256;
                int row = slot >> 4, c = (slot & 15) * 16;
                gload16(kg + (size_t)(kv0 + row) * 256 + (c ^ ((row & 7) << 4)),
                        lKc + bf * 16384 + slot * 16);
            }
            #pragma unroll
            for (int i = 0; i < 4; i++) {
                int slot = tid + i * 256;
                int d = slot >> 3, c = (slot & 7) * 16;
                gload16(vg + (size_t)d * 4096 + (size_t)kv0 * 2 + (c ^ ((d & 7) << 4)),
                        lVc + bf * 16384 + slot * 16);
            }
        };

        const int ntiles = (qbase >> 6) + 2;   // >= 2 always
        stageKV(0, 0);
        if (ntiles > 1) stageKV(1, 64);

        for (int it = 0; it < ntiles; it++) {
            const int kv0 = it * 64;
            const int buf = it & 1;
            if (it + 1 < ntiles) asm volatile("s_waitcnt vmcnt(8)" ::: "memory");
            else                 asm volatile("s_waitcnt vmcnt(0)" ::: "memory");
            __builtin_amdgcn_s_barrier();

            if (kv0 <= qw + 31) {   // wave-active (causal range)
                const char* lKb = lKc + buf * 16384;
                const char* lVb = lVc + buf * 16384;

                f32x4 s[2][4] = {};
                #pragma unroll
                for (int ks = 0; ks < 4; ks++) {
                    bf16x8 kf[4];
                    #pragma unroll
                    for (int nt = 0; nt < 4; nt++) {
                        int row = nt * 16 + ln15;
                        kf[nt] = *(const bf16x8*)(lKb + row * 256 + (((ks * 32 + hi8) * 2) ^ ((row & 7) << 4)));
                    }
                    __builtin_amdgcn_s_setprio(1);
                    #pragma unroll
                    for (int mt = 0; mt < 2; mt++)
                        #pragma unroll
                        for (int nt = 0; nt < 4; nt++)
                            s[mt][nt] = __builtin_amdgcn_mfma_f32_16x16x32_bf16(kf[nt], qf[mt][ks], s[mt][nt], 0, 0, 0);
                    __builtin_amdgcn_s_setprio(0);
                }

                if (kv0 + 63 > qw) {  // diagonal tile: mask kv > q
                    #pragma unroll
                    for (int mt = 0; mt < 2; mt++) {
                        int qi = qw + mt * 16 + ln15;
                        #pragma unroll
                        for (int nt = 0; nt < 4; nt++)
                            #pragma unroll
                            for (int j = 0; j < 4; j++) {
                                int kvi = kv0 + nt * 16 + 4 * hig + j;
                                if (kvi > qi) s[mt][nt][j] = -1e30f;
                            }
                    }
                }

                float vmax[2];
                #pragma unroll
                for (int mt = 0; mt < 2; mt++) {
                    float v = fmaxf(fmaxf(s[mt][0][0], s[mt][0][1]), fmaxf(s[mt][0][2], s[mt][0][3]));
                    #pragma unroll
                    for (int nt = 1; nt < 4; nt++)
                        v = fmaxf(v, fmaxf(fmaxf(s[mt][nt][0], s[mt][nt][1]), fmaxf(s[mt][nt][2], s[mt][nt][3])));
                    v = fmaxf(v, __shfl_xor(v, 16));
                    v = fmaxf(v, __shfl_xor(v, 32));
                    vmax[mt] = v;
                }
                bool grow = (vmax[0] > mreg[0] + 8.0f) || (vmax[1] > mreg[1] + 8.0f);
                if (__any(grow)) {
                    float sc[2];
                    #pragma unroll
                    for (int mt = 0; mt < 2; mt++) {
                        float mn = fmaxf(mreg[mt], vmax[mt]);
                        sc[mt] = __expf(mreg[mt] - mn);
                        mreg[mt] = mn;
                        lreg[mt] *= sc[mt];
                    }
                    #pragma unroll
                    for (int mt = 0; mt < 2; mt++)
                        #pragma unroll
                        for (int j = 0; j < 4; j++) {
                            float scj = __shfl(sc[mt], 4 * hig + j);
                            #pragma unroll
                            for (int ntd = 0; ntd < 8; ntd++) o[mt][ntd][j] *= scj;
                        }
                }
                #pragma unroll
                for (int mt = 0; mt < 2; mt++) {
                    float rs = 0.f;
                    #pragma unroll
                    for (int nt = 0; nt < 4; nt++)
                        #pragma unroll
                        for (int j = 0; j < 4; j++) {
                            float p = __expf(s[mt][nt][j] - mreg[mt]);
                            s[mt][nt][j] = p;
                            rs += p;
                        }
                    rs += __shfl_xor(rs, 16);
                    rs += __shfl_xor(rs, 32);
                    lreg[mt] += rs;
                }

                #pragma unroll
                for (int mt = 0; mt < 2; mt++) {
                    int rr = mt * 16 + ln15;
                    int rx = (rr & 7) << 4;
                    #pragma unroll
                    for (int nt = 0; nt < 4; nt++) {
                        us4 pk = { f2bf(s[mt][nt][0]), f2bf(s[mt][nt][1]),
                                   f2bf(s[mt][nt][2]), f2bf(s[mt][nt][3]) };
                        int addr = rr * 128 + ((nt * 32 + hig * 8) ^ rx);
                        *(us4*)(lPc + addr) = pk;
                    }
                }

                #pragma unroll
                for (int ks2 = 0; ks2 < 2; ks2++) {
                    bf16x8 pf[2];
                    #pragma unroll
                    for (int mt = 0; mt < 2; mt++) {
                        int row = mt * 16 + ln15;
                        pf[mt] = *(const bf16x8*)(lPc + row * 128 + (((ks2 * 32 + hi8) * 2) ^ ((row & 7) << 4)));
                    }
                    #pragma unroll
                    for (int ntd = 0; ntd < 8; ntd++) {
                        int drow = ntd * 16 + ln15;
                        bf16x8 vf = *(const bf16x8*)(lVb + drow * 128 + (((ks2 * 32 + hi8) * 2) ^ ((drow & 7) << 4)));
                        __builtin_amdgcn_s_setprio(1);
                        #pragma unroll
                        for (int mt = 0; mt < 2; mt++)
                            o[mt][ntd] = __builtin_amdgcn_mfma_f32_16x16x32_bf16(pf[mt], vf, o[mt][ntd], 0, 0, 0);
                        __builtin_amdgcn_s_setprio(0);
                    }
                }
            }

            __builtin_amdgcn_s_barrier();
            if (it + 2 < ntiles) stageKV(buf, kv0 + 128);
        }

        #pragma unroll
        for (int mt = 0; mt < 2; mt++)
            #pragma unroll
            for (int j = 0; j < 4; j++) {
                float inv = 1.0f / __shfl(lreg[mt], 4 * hig + j);
                int t = qw + mt * 16 + hig * 4 + j;
                #pragma unroll
                for (int ntd = 0; ntd < 8; ntd++) {
                    int d = ntd * 16 + ln15;
                    outp[((size_t)b * 2048 + t) * 2048 + h * 128 + d] = f2bf(o[mt][ntd][j] * inv);
                }
            }
    }
}

// ---------- launcher ----------
extern "C" void kernel_launch(void* const* d_in, const int* in_sizes, int n_in,
                              void* d_out, int out_size, void* d_ws, size_t ws_size,
                              hipStream_t stream) {
    const float* x     = (const float*)d_in[0];
    const float* wqkv  = (const float*)d_in[1];
    const float* wo    = (const float*)d_in[2];
    const float* ropeC = (const float*)d_in[3];
    const float* ropeS = (const float*)d_in[4];
    float* out = (float*)d_out;
    char* ws = (char*)d_ws;
    const size_t MB = 1024 * 1024;
    unsigned short* xb    = (unsigned short*)(ws);                  // 32 MB
    unsigned short* wqkvT = (unsigned short*)(ws + 32 * MB);        // 24 MB
    unsigned short* woT   = (unsigned short*)(ws + 56 * MB);        // 8 MB
    unsigned short* qb    = (unsigned short*)(ws + 64 * MB);        // 32 MB
    unsigned short* kb    = (unsigned short*)(ws + 96 * MB);        // 32 MB
    unsigned short* vTb   = (unsigned short*)(ws + 128 * MB);       // 32 MB
    unsigned short* attnb = (unsigned short*)(ws + 160 * MB);       // 32 MB

    cvt_f32_bf16<<<16384, 256, 0, stream>>>(x, xb, 4194304);
    tcvt<<<dim3(192, 64), 256, 0, stream>>>(wqkv, wqkvT, 2048, 6144);
    tcvt<<<dim3(64, 64), 256, 0, stream>>>(wo, woT, 2048, 2048);
    gemmw<1><<<dim3(24, 32), 1024, 0, stream>>>(xb, wqkvT, 8192, 6144, 2048,
                                                nullptr, qb, kb, vTb, ropeC, ropeS, 8, 12);
    attn_fwd<<<dim3(64, 8), 256, 0, stream>>>(qb, kb, vTb, attnb);
    gemmw<0><<<dim3(8, 32), 1024, 0, stream>>>(attnb, woT, 8192, 2048, 2048,
                                               out, nullptr, nullptr, nullptr, nullptr, nullptr, 4, 8);
}

// Round 15
// 400.945 us; speedup vs baseline: 1.0701x; 1.0034x over previous
//
#include <hip/hip_runtime.h>
#include <hip/hip_bf16.h>

// ---------- types ----------
typedef __attribute__((ext_vector_type(8))) __bf16 bf16x8;
typedef __attribute__((ext_vector_type(4))) float f32x4;
typedef __attribute__((ext_vector_type(4))) unsigned short us4;

__device__ __forceinline__ unsigned short f2bf(float f) {
    unsigned u = __float_as_uint(f);
    u += 0x7FFFu + ((u >> 16) & 1u);   // RNE
    return (unsigned short)(u >> 16);
}

__device__ __forceinline__ void gload16(const void* g, void* l) {
    __builtin_amdgcn_global_load_lds(
        (const __attribute__((address_space(1))) unsigned int*)g,
        (__attribute__((address_space(3))) unsigned int*)l,
        16, 0, 0);
}

// ---------- kernel 1: fp32 -> bf16 (x), grid-stride (G11: cap blocks, amortize dispatch) ----------
__global__ void cvt_f32_bf16(const float* __restrict__ in, unsigned short* __restrict__ out, int n4) {
    int stride = gridDim.x * blockDim.x;
    for (int i = blockIdx.x * blockDim.x + threadIdx.x; i < n4; i += stride) {
        float4 v = ((const float4*)in)[i];
        us4 r = { f2bf(v.x), f2bf(v.y), f2bf(v.z), f2bf(v.w) };
        ((us4*)out)[i] = r;
    }
}

// ---------- kernel 2: transpose + convert: in[R][C] f32 -> out[C][R] bf16 ----------
__global__ void tcvt(const float* __restrict__ in, unsigned short* __restrict__ out, int R, int C) {
    __shared__ float tile[32][33];
    int tx = threadIdx.x & 31, ty = threadIdx.x >> 5;  // 256 threads
    int c0 = blockIdx.x * 32, r0 = blockIdx.y * 32;
    #pragma unroll
    for (int i = 0; i < 32; i += 8)
        tile[ty + i][tx] = in[(size_t)(r0 + ty + i) * C + c0 + tx];
    __syncthreads();
    #pragma unroll
    for (int i = 0; i < 32; i += 8)
        out[(size_t)(c0 + ty + i) * R + r0 + tx] = f2bf(tile[tx][ty + i]);
}

// ---------- 256x256 GEMM, 16 waves (1024 thr), per-wave 64x64, BK=64, dbuf (R8/R10 proven) ----------
// LDS per buf (64 KB): A = 256 rows x 128B at [0,32K), B at [32K,64K). Buf stride 64K.
// Row layout: 8 x 16B slots; slot h of row r holds k-group h ^ (r&7)  (2-way read conflicts = free).
// TLP design: 4 waves/SIMD (VGPR 56); no setprio (flat on lockstep GEMM, m190/R10).
// NOTE (R11/R13 ledger): 32x32 MFMA shape = structural 4-way LDS conflict at 128B row
// pitch (bank = f(slot) only; pigeonhole 32 rows -> 8 slots); BK=32 doubles sync for no
// co-residency gain. 16x16 + BK=64 is the optimum of this geometry.
#define MFW(af, bf, fi, ni) acc[fi][ni] = __builtin_amdgcn_mfma_f32_16x16x32_bf16(af, bf, acc[fi][ni], 0, 0, 0)
#define MFMA16W() do { \
    MFW(a0,b0,0,0); MFW(a0,b1,0,1); MFW(a0,b2,0,2); MFW(a0,b3,0,3); \
    MFW(a1,b0,1,0); MFW(a1,b1,1,1); MFW(a1,b2,1,2); MFW(a1,b3,1,3); \
    MFW(a2,b0,2,0); MFW(a2,b1,2,1); MFW(a2,b2,2,2); MFW(a2,b3,2,3); \
    MFW(a3,b0,3,0); MFW(a3,b1,3,1); MFW(a3,b2,3,2); MFW(a3,b3,3,3); } while(0)
#define STGW(kt, bufo) do { \
    size_t ko = (size_t)(kt) * 128; \
    char* bb = L + (bufo); \
    gload16(Ag + sR + ko, bb + dstA); \
    gload16(Ag + sR2 + ko, bb + dstA + 16384); \
    gload16(Bg + sR + ko, bb + 32768 + dstA); \
    gload16(Bg + sR2 + ko, bb + 32768 + dstA + 16384); } while (0)

template <int MODE>
__global__ __launch_bounds__(1024, 4) void gemmw(
    const unsigned short* __restrict__ A, const unsigned short* __restrict__ Bt,
    int M, int N, int K, float* __restrict__ Cf,
    unsigned short* __restrict__ qp, unsigned short* __restrict__ kp,
    unsigned short* __restrict__ vTp,
    const float* __restrict__ ropeC, const float* __restrict__ ropeS,
    int cby, int cbx)
{
    __shared__ unsigned short lds[2][32768];   // 128 KB
    const int tid = threadIdx.x;
    const int lane = tid & 63, wid = tid >> 6;      // wid 0..15
    const int ln15 = lane & 15, hig = lane >> 4;
    const int wrow = wid >> 2, wcol = wid & 3;      // 4x4 wave grid, 64x64 each

    int nwg = gridDim.x * gridDim.y;
    int flat = blockIdx.y * gridDim.x + blockIdx.x;
    int bx, by;
    if ((nwg & 7) == 0) {
        int c = flat & 7, local = flat >> 3;
        int chunkCols = gridDim.x / cbx;
        by = (c / chunkCols) * cby + local / cbx;
        bx = (c % chunkCols) * cbx + local % cbx;
    } else {
        bx = flat % gridDim.x; by = flat / gridDim.x;
    }
    const int mbase = by * 256, nbase = bx * 256;
    const size_t Kb = (size_t)K * 2;

    const char* Ag = (const char*)A + (size_t)mbase * Kb;
    const char* Bg = (const char*)Bt + (size_t)nbase * Kb;
    char* L = (char*)&lds[0][0];

    const int srow = tid >> 3;
    const int gs = (tid & 7) ^ (srow & 7);
    const size_t sR = (size_t)srow * Kb + gs * 16;
    const size_t sR2 = sR + (size_t)128 * Kb;
    const int dstA = tid * 16;

    const int aBase = (wrow * 64 + ln15) * 128;
    const int bBase = 32768 + (wcol * 64 + ln15) * 128;
    const int sl0 = (hig ^ (ln15 & 7)) * 16;
    const int sl1 = ((4 + hig) ^ (ln15 & 7)) * 16;

    f32x4 acc[4][4] = {};
    const int T = K >> 6;

    STGW(0, 0);
    asm volatile("s_waitcnt vmcnt(0)" ::: "memory");
    __builtin_amdgcn_s_barrier();
    asm volatile("" ::: "memory");

    for (int t = 0; t < T; t++) {
        char* bb = L + (t & 1) * 65536;
        if (t + 1 < T) STGW(t + 1, ((t + 1) & 1) * 65536);
        bf16x8 a0, a1, a2, a3, b0, b1, b2, b3;
        // kk0
        a0 = *(const bf16x8*)(bb + aBase + 0 * 2048 + sl0);
        a1 = *(const bf16x8*)(bb + aBase + 1 * 2048 + sl0);
        a2 = *(const bf16x8*)(bb + aBase + 2 * 2048 + sl0);
        a3 = *(const bf16x8*)(bb + aBase + 3 * 2048 + sl0);
        b0 = *(const bf16x8*)(bb + bBase + 0 * 2048 + sl0);
        b1 = *(const bf16x8*)(bb + bBase + 1 * 2048 + sl0);
        b2 = *(const bf16x8*)(bb + bBase + 2 * 2048 + sl0);
        b3 = *(const bf16x8*)(bb + bBase + 3 * 2048 + sl0);
        MFMA16W();
        // kk1
        a0 = *(const bf16x8*)(bb + aBase + 0 * 2048 + sl1);
        a1 = *(const bf16x8*)(bb + aBase + 1 * 2048 + sl1);
        a2 = *(const bf16x8*)(bb + aBase + 2 * 2048 + sl1);
        a3 = *(const bf16x8*)(bb + aBase + 3 * 2048 + sl1);
        b0 = *(const bf16x8*)(bb + bBase + 0 * 2048 + sl1);
        b1 = *(const bf16x8*)(bb + bBase + 1 * 2048 + sl1);
        b2 = *(const bf16x8*)(bb + bBase + 2 * 2048 + sl1);
        b3 = *(const bf16x8*)(bb + bBase + 3 * 2048 + sl1);
        MFMA16W();

        if (t + 1 < T) {
            asm volatile("s_waitcnt vmcnt(0)" ::: "memory");
            __builtin_amdgcn_s_barrier();
            asm volatile("" ::: "memory");
        }
    }

    if (MODE == 0) {
        #pragma unroll
        for (int fm = 0; fm < 4; fm++)
            #pragma unroll
            for (int fn = 0; fn < 4; fn++)
                #pragma unroll
                for (int j = 0; j < 4; j++) {
                    int m = mbase + wrow * 64 + fm * 16 + hig * 4 + j;
                    int col = nbase + wcol * 64 + fn * 16 + ln15;
                    Cf[(size_t)m * N + col] = acc[fm][fn][j];
                }
    } else {
        const int colb = nbase + wcol * 64;
        const int sec = colb >> 11;               // 0=q, 1=k, 2=v
        if (sec < 2) {
            unsigned short* dst = (sec == 0) ? qp : kp;
            const float scale = (sec == 0) ? 0.08838834764831845f : 1.0f;
            #pragma unroll
            for (int fm = 0; fm < 4; fm++)
                #pragma unroll
                for (int fn = 0; fn < 4; fn++) {
                    int within = (colb & 2047) + fn * 16 + ln15;
                    int h = within >> 7, d = within & 127, pidx = d >> 1;
                    #pragma unroll
                    for (int j = 0; j < 4; j++) {
                        int m = mbase + wrow * 64 + fm * 16 + hig * 4 + j;
                        int b = m >> 11, tq = m & 2047;
                        float v = acc[fm][fn][j];
                        float pv = __shfl_xor(v, 1);
                        float c = ropeC[tq * 64 + pidx], s = ropeS[tq * 64 + pidx];
                        float o = (d & 1) ? fmaf(pv, s, v * c) : fmaf(-pv, s, v * c);
                        o *= scale;
                        dst[((size_t)((b << 4) + h) * 2048 + tq) * 128 + d] = f2bf(o);
                    }
                }
        } else {
            #pragma unroll
            for (int fm = 0; fm < 4; fm++)
                #pragma unroll
                for (int fn = 0; fn < 4; fn++) {
                    int within = (colb & 2047) + fn * 16 + ln15;
                    int h = within >> 7, d = within & 127;
                    int m0 = mbase + wrow * 64 + fm * 16 + hig * 4;
                    int b = m0 >> 11, t0 = m0 & 2047;
                    us4 pk = { f2bf(acc[fm][fn][0]), f2bf(acc[fm][fn][1]),
                               f2bf(acc[fm][fn][2]), f2bf(acc[fm][fn][3]) };
                    *(us4*)(vTp + ((size_t)((b << 4) + h) * 128 + d) * 2048 + t0) = pk;
                }
        }
    }
}

// ---------- flash attention (R10 proven): causal, swapped QK^T, KVBLK=64, dbuf, counted vmcnt ----------
// grid: (64, 8)  x = bh (XCD locality), y = q-pair.  q,k: [BH][T][D] (q pre-scaled); vT: [BH][D][T]
__global__ __launch_bounds__(256, 2) void attn_fwd(
    const unsigned short* __restrict__ q, const unsigned short* __restrict__ k,
    const unsigned short* __restrict__ vT, unsigned short* __restrict__ outp)
{
    __shared__ unsigned short lK[2][64 * 128];   // 2 x 16 KB, [kv][d], XOR-swizzled rows (256B)
    __shared__ unsigned short lV[2][128 * 64];   // 2 x 16 KB, [d][kv], XOR-swizzled rows (128B)
    __shared__ unsigned short lP[4 * 32 * 64];   // 16 KB, per-wave
    const int tid = threadIdx.x;
    const int lane = tid & 63, wid = tid >> 6;
    const int ln15 = lane & 15, hig = lane >> 4, hi8 = hig * 8;
    const int bh = blockIdx.x;

    const char* qg = (const char*)(q + (size_t)bh * 2048 * 128);
    const char* kg = (const char*)(k + (size_t)bh * 2048 * 128);
    const char* vg = (const char*)(vT + (size_t)bh * 128 * 2048);
    char* lKc = (char*)&lK[0][0];
    char* lVc = (char*)&lV[0][0];
    char* lPc = (char*)lP + wid * (32 * 64 * 2);
    const int b = bh >> 4, h = bh & 15;

    for (int rep = 0; rep < 2; rep++) {
        const int qt = rep == 0 ? (int)blockIdx.y : 15 - (int)blockIdx.y;
        const int qbase = qt * 128;
        const int qw = qbase + wid * 32;

        bf16x8 qf[2][4];
        #pragma unroll
        for (int mt = 0; mt < 2; mt++)
            #pragma unroll
            for (int ks = 0; ks < 4; ks++)
                qf[mt][ks] = *(const bf16x8*)(qg + ((size_t)(qw + mt * 16 + ln15) * 128 + ks * 32 + hi8) * 2);

        f32x4 o[2][8] = {};
        float mreg[2] = { -1e30f, -1e30f };
        float lreg[2] = { 0.f, 0.f };

        auto stageKV = [&](int bf, int kv0) {
            #pragma unroll
            for (int i = 0; i < 4; i++) {
                int slot = tid + i * 256;
                int row = slot >> 4, c = (slot & 15) * 16;
                gload16(kg + (size_t)(kv0 + row) * 256 + (c ^ ((row & 7) << 4)),
                        lKc + bf * 16384 + slot * 16);
            }
            #pragma unroll
            for (int i = 0; i < 4; i++) {
                int slot = tid + i * 256;
                int d = slot >> 3, c = (slot & 7) * 16;
                gload16(vg + (size_t)d * 4096 + (size_t)kv0 * 2 + (c ^ ((d & 7) << 4)),
                        lVc + bf * 16384 + slot * 16);
            }
        };

        const int ntiles = (qbase >> 6) + 2;   // >= 2 always
        stageKV(0, 0);
        if (ntiles > 1) stageKV(1, 64);

        for (int it = 0; it < ntiles; it++) {
            const int kv0 = it * 64;
            const int buf = it & 1;
            if (it + 1 < ntiles) asm volatile("s_waitcnt vmcnt(8)" ::: "memory");
            else                 asm volatile("s_waitcnt vmcnt(0)" ::: "memory");
            __builtin_amdgcn_s_barrier();

            if (kv0 <= qw + 31) {   // wave-active (causal range)
                const char* lKb = lKc + buf * 16384;
                const char* lVb = lVc + buf * 16384;

                f32x4 s[2][4] = {};
                #pragma unroll
                for (int ks = 0; ks < 4; ks++) {
                    bf16x8 kf[4];
                    #pragma unroll
                    for (int nt = 0; nt < 4; nt++) {
                        int row = nt * 16 + ln15;
                        kf[nt] = *(const bf16x8*)(lKb + row * 256 + (((ks * 32 + hi8) * 2) ^ ((row & 7) << 4)));
                    }
                    __builtin_amdgcn_s_setprio(1);
                    #pragma unroll
                    for (int mt = 0; mt < 2; mt++)
                        #pragma unroll
                        for (int nt = 0; nt < 4; nt++)
                            s[mt][nt] = __builtin_amdgcn_mfma_f32_16x16x32_bf16(kf[nt], qf[mt][ks], s[mt][nt], 0, 0, 0);
                    __builtin_amdgcn_s_setprio(0);
                }

                if (kv0 + 63 > qw) {  // diagonal tile: mask kv > q
                    #pragma unroll
                    for (int mt = 0; mt < 2; mt++) {
                        int qi = qw + mt * 16 + ln15;
                        #pragma unroll
                        for (int nt = 0; nt < 4; nt++)
                            #pragma unroll
                            for (int j = 0; j < 4; j++) {
                                int kvi = kv0 + nt * 16 + 4 * hig + j;
                                if (kvi > qi) s[mt][nt][j] = -1e30f;
                            }
                    }
                }

                float vmax[2];
                #pragma unroll
                for (int mt = 0; mt < 2; mt++) {
                    float v = fmaxf(fmaxf(s[mt][0][0], s[mt][0][1]), fmaxf(s[mt][0][2], s[mt][0][3]));
                    #pragma unroll
                    for (int nt = 1; nt < 4; nt++)
                        v = fmaxf(v, fmaxf(fmaxf(s[mt][nt][0], s[mt][nt][1]), fmaxf(s[mt][nt][2], s[mt][nt][3])));
                    v = fmaxf(v, __shfl_xor(v, 16));
                    v = fmaxf(v, __shfl_xor(v, 32));
                    vmax[mt] = v;
                }
                bool grow = (vmax[0] > mreg[0] + 8.0f) || (vmax[1] > mreg[1] + 8.0f);
                if (__any(grow)) {
                    float sc[2];
                    #pragma unroll
                    for (int mt = 0; mt < 2; mt++) {
                        float mn = fmaxf(mreg[mt], vmax[mt]);
                        sc[mt] = __expf(mreg[mt] - mn);
                        mreg[mt] = mn;
                        lreg[mt] *= sc[mt];
                    }
                    #pragma unroll
                    for (int mt = 0; mt < 2; mt++)
                        #pragma unroll
                        for (int j = 0; j < 4; j++) {
                            float scj = __shfl(sc[mt], 4 * hig + j);
                            #pragma unroll
                            for (int ntd = 0; ntd < 8; ntd++) o[mt][ntd][j] *= scj;
                        }
                }
                #pragma unroll
                for (int mt = 0; mt < 2; mt++) {
                    float rs = 0.f;
                    #pragma unroll
                    for (int nt = 0; nt < 4; nt++)
                        #pragma unroll
                        for (int j = 0; j < 4; j++) {
                            float p = __expf(s[mt][nt][j] - mreg[mt]);
                            s[mt][nt][j] = p;
                            rs += p;
                        }
                    rs += __shfl_xor(rs, 16);
                    rs += __shfl_xor(rs, 32);
                    lreg[mt] += rs;
                }

                #pragma unroll
                for (int mt = 0; mt < 2; mt++) {
                    int rr = mt * 16 + ln15;
                    int rx = (rr & 7) << 4;
                    #pragma unroll
                    for (int nt = 0; nt < 4; nt++) {
                        us4 pk = { f2bf(s[mt][nt][0]), f2bf(s[mt][nt][1]),
                                   f2bf(s[mt][nt][2]), f2bf(s[mt][nt][3]) };
                        int addr = rr * 128 + ((nt * 32 + hig * 8) ^ rx);
                        *(us4*)(lPc + addr) = pk;
                    }
                }

                #pragma unroll
                for (int ks2 = 0; ks2 < 2; ks2++) {
                    bf16x8 pf[2];
                    #pragma unroll
                    for (int mt = 0; mt < 2; mt++) {
                        int row = mt * 16 + ln15;
                        pf[mt] = *(const bf16x8*)(lPc + row * 128 + (((ks2 * 32 + hi8) * 2) ^ ((row & 7) << 4)));
                    }
                    #pragma unroll
                    for (int ntd = 0; ntd < 8; ntd++) {
                        int drow = ntd * 16 + ln15;
                        bf16x8 vf = *(const bf16x8*)(lVb + drow * 128 + (((ks2 * 32 + hi8) * 2) ^ ((drow & 7) << 4)));
                        __builtin_amdgcn_s_setprio(1);
                        #pragma unroll
                        for (int mt = 0; mt < 2; mt++)
                            o[mt][ntd] = __builtin_amdgcn_mfma_f32_16x16x32_bf16(pf[mt], vf, o[mt][ntd], 0, 0, 0);
                        __builtin_amdgcn_s_setprio(0);
                    }
                }
            }

            __builtin_amdgcn_s_barrier();
            if (it + 2 < ntiles) stageKV(buf, kv0 + 128);
        }

        #pragma unroll
        for (int mt = 0; mt < 2; mt++)
            #pragma unroll
            for (int j = 0; j < 4; j++) {
                float inv = 1.0f / __shfl(lreg[mt], 4 * hig + j);
                int t = qw + mt * 16 + hig * 4 + j;
                #pragma unroll
                for (int ntd = 0; ntd < 8; ntd++) {
                    int d = ntd * 16 + ln15;
                    outp[((size_t)b * 2048 + t) * 2048 + h * 128 + d] = f2bf(o[mt][ntd][j] * inv);
                }
            }
    }
}

// ---------- launcher ----------
extern "C" void kernel_launch(void* const* d_in, const int* in_sizes, int n_in,
                              void* d_out, int out_size, void* d_ws, size_t ws_size,
                              hipStream_t stream) {
    const float* x     = (const float*)d_in[0];
    const float* wqkv  = (const float*)d_in[1];
    const float* wo    = (const float*)d_in[2];
    const float* ropeC = (const float*)d_in[3];
    const float* ropeS = (const float*)d_in[4];
    float* out = (float*)d_out;
    char* ws = (char*)d_ws;
    const size_t MB = 1024 * 1024;
    unsigned short* xb    = (unsigned short*)(ws);                  // 32 MB
    unsigned short* wqkvT = (unsigned short*)(ws + 32 * MB);        // 24 MB
    unsigned short* woT   = (unsigned short*)(ws + 56 * MB);        // 8 MB
    unsigned short* qb    = (unsigned short*)(ws + 64 * MB);        // 32 MB
    unsigned short* kb    = (unsigned short*)(ws + 96 * MB);        // 32 MB
    unsigned short* vTb   = (unsigned short*)(ws + 128 * MB);       // 32 MB
    unsigned short* attnb = (unsigned short*)(ws + 160 * MB);       // 32 MB

    cvt_f32_bf16<<<2048, 256, 0, stream>>>(x, xb, 4194304);
    tcvt<<<dim3(192, 64), 256, 0, stream>>>(wqkv, wqkvT, 2048, 6144);
    tcvt<<<dim3(64, 64), 256, 0, stream>>>(wo, woT, 2048, 2048);
    gemmw<1><<<dim3(24, 32), 1024, 0, stream>>>(xb, wqkvT, 8192, 6144, 2048,
                                                nullptr, qb, kb, vTb, ropeC, ropeS, 8, 12);
    attn_fwd<<<dim3(64, 8), 256, 0, stream>>>(qb, kb, vTb, attnb);
    gemmw<0><<<dim3(8, 32), 1024, 0, stream>>>(attnb, woT, 8192, 2048, 2048,
                                               out, nullptr, nullptr, nullptr, nullptr, nullptr, 4, 8);
}

// Round 16
// 400.197 us; speedup vs baseline: 1.0721x; 1.0019x over previous
//
#include <hip/hip_runtime.h>
#include <hip/hip_bf16.h>

// ---------- types ----------
typedef __attribute__((ext_vector_type(8))) __bf16 bf16x8;
typedef __attribute__((ext_vector_type(4))) float f32x4;
typedef __attribute__((ext_vector_type(4))) unsigned short us4;

__device__ __forceinline__ unsigned short f2bf(float f) {
    unsigned u = __float_as_uint(f);
    u += 0x7FFFu + ((u >> 16) & 1u);   // RNE
    return (unsigned short)(u >> 16);
}

__device__ __forceinline__ void gload16(const void* g, void* l) {
    __builtin_amdgcn_global_load_lds(
        (const __attribute__((address_space(1))) unsigned int*)g,
        (__attribute__((address_space(3))) unsigned int*)l,
        16, 0, 0);
}

// ---------- kernel 1: fp32 -> bf16 (x), grid-stride ----------
__global__ void cvt_f32_bf16(const float* __restrict__ in, unsigned short* __restrict__ out, int n4) {
    int stride = gridDim.x * blockDim.x;
    for (int i = blockIdx.x * blockDim.x + threadIdx.x; i < n4; i += stride) {
        float4 v = ((const float4*)in)[i];
        us4 r = { f2bf(v.x), f2bf(v.y), f2bf(v.z), f2bf(v.w) };
        ((us4*)out)[i] = r;
    }
}

// ---------- kernel 2: transpose + convert: in[R][C] f32 -> out[C][R] bf16 ----------
// 32(r) x 64(c) tile, 256 threads. Loads float4-coalesced; stores us4 (8B/lane):
// 4 lanes cover a 64B out-row segment -> 1KB per wave-store (was 128B at 2B/lane).
// LDS pitch 69 floats: store-phase read banks = (lc + 8k) mod 32 -> exactly 2-way (free, m136).
__global__ void tcvt(const float* __restrict__ in, unsigned short* __restrict__ out, int R, int C) {
    __shared__ float tile[32][69];
    const int t = threadIdx.x;
    const int c0 = blockIdx.x * 64, r0 = blockIdx.y * 32;
    #pragma unroll
    for (int i = 0; i < 2; i++) {
        int rl = (t >> 4) + i * 16;
        int cl = (t & 15) * 4;
        float4 v = *(const float4*)(in + (size_t)(r0 + rl) * C + c0 + cl);
        tile[rl][cl + 0] = v.x; tile[rl][cl + 1] = v.y;
        tile[rl][cl + 2] = v.z; tile[rl][cl + 3] = v.w;
    }
    __syncthreads();
    const int lc = t >> 2;
    #pragma unroll
    for (int g = 0; g < 2; g++) {
        int rr = (t & 3) * 8 + g * 4;
        us4 pk = { f2bf(tile[rr + 0][lc]), f2bf(tile[rr + 1][lc]),
                   f2bf(tile[rr + 2][lc]), f2bf(tile[rr + 3][lc]) };
        *(us4*)(out + (size_t)(c0 + lc) * R + r0 + rr) = pk;
    }
}

// ---------- 256x256 GEMM, 16 waves (1024 thr), per-wave 64x64, BK=64, dbuf (R8/R10 proven) ----------
// LDS per buf (64 KB): A = 256 rows x 128B at [0,32K), B at [32K,64K). Buf stride 64K.
// Row layout: 8 x 16B slots; slot h of row r holds k-group h ^ (r&7)  (2-way read conflicts = free).
// TLP design: 4 waves/SIMD (VGPR 56); no setprio (flat on lockstep GEMM, m190/R10).
// NOTE (R11/R13 ledger): 32x32 MFMA shape = structural 4-way LDS conflict at 128B row
// pitch; BK=32 doubles sync for no co-residency gain. 16x16 + BK=64 is this geometry's optimum.
#define MFW(af, bf, fi, ni) acc[fi][ni] = __builtin_amdgcn_mfma_f32_16x16x32_bf16(af, bf, acc[fi][ni], 0, 0, 0)
#define MFMA16W() do { \
    MFW(a0,b0,0,0); MFW(a0,b1,0,1); MFW(a0,b2,0,2); MFW(a0,b3,0,3); \
    MFW(a1,b0,1,0); MFW(a1,b1,1,1); MFW(a1,b2,1,2); MFW(a1,b3,1,3); \
    MFW(a2,b0,2,0); MFW(a2,b1,2,1); MFW(a2,b2,2,2); MFW(a2,b3,2,3); \
    MFW(a3,b0,3,0); MFW(a3,b1,3,1); MFW(a3,b2,3,2); MFW(a3,b3,3,3); } while(0)
#define STGW(kt, bufo) do { \
    size_t ko = (size_t)(kt) * 128; \
    char* bb = L + (bufo); \
    gload16(Ag + sR + ko, bb + dstA); \
    gload16(Ag + sR2 + ko, bb + dstA + 16384); \
    gload16(Bg + sR + ko, bb + 32768 + dstA); \
    gload16(Bg + sR2 + ko, bb + 32768 + dstA + 16384); } while (0)

template <int MODE>
__global__ __launch_bounds__(1024, 4) void gemmw(
    const unsigned short* __restrict__ A, const unsigned short* __restrict__ Bt,
    int M, int N, int K, float* __restrict__ Cf,
    unsigned short* __restrict__ qp, unsigned short* __restrict__ kp,
    unsigned short* __restrict__ vTp,
    const float* __restrict__ ropeC, const float* __restrict__ ropeS,
    int cby, int cbx)
{
    __shared__ unsigned short lds[2][32768];   // 128 KB
    const int tid = threadIdx.x;
    const int lane = tid & 63, wid = tid >> 6;      // wid 0..15
    const int ln15 = lane & 15, hig = lane >> 4;
    const int wrow = wid >> 2, wcol = wid & 3;      // 4x4 wave grid, 64x64 each

    int nwg = gridDim.x * gridDim.y;
    int flat = blockIdx.y * gridDim.x + blockIdx.x;
    int bx, by;
    if ((nwg & 7) == 0) {
        int c = flat & 7, local = flat >> 3;
        int chunkCols = gridDim.x / cbx;
        by = (c / chunkCols) * cby + local / cbx;
        bx = (c % chunkCols) * cbx + local % cbx;
    } else {
        bx = flat % gridDim.x; by = flat / gridDim.x;
    }
    const int mbase = by * 256, nbase = bx * 256;
    const size_t Kb = (size_t)K * 2;

    const char* Ag = (const char*)A + (size_t)mbase * Kb;
    const char* Bg = (const char*)Bt + (size_t)nbase * Kb;
    char* L = (char*)&lds[0][0];

    const int srow = tid >> 3;
    const int gs = (tid & 7) ^ (srow & 7);
    const size_t sR = (size_t)srow * Kb + gs * 16;
    const size_t sR2 = sR + (size_t)128 * Kb;
    const int dstA = tid * 16;

    const int aBase = (wrow * 64 + ln15) * 128;
    const int bBase = 32768 + (wcol * 64 + ln15) * 128;
    const int sl0 = (hig ^ (ln15 & 7)) * 16;
    const int sl1 = ((4 + hig) ^ (ln15 & 7)) * 16;

    f32x4 acc[4][4] = {};
    const int T = K >> 6;

    STGW(0, 0);
    asm volatile("s_waitcnt vmcnt(0)" ::: "memory");
    __builtin_amdgcn_s_barrier();
    asm volatile("" ::: "memory");

    for (int t = 0; t < T; t++) {
        char* bb = L + (t & 1) * 65536;
        if (t + 1 < T) STGW(t + 1, ((t + 1) & 1) * 65536);
        bf16x8 a0, a1, a2, a3, b0, b1, b2, b3;
        // kk0
        a0 = *(const bf16x8*)(bb + aBase + 0 * 2048 + sl0);
        a1 = *(const bf16x8*)(bb + aBase + 1 * 2048 + sl0);
        a2 = *(const bf16x8*)(bb + aBase + 2 * 2048 + sl0);
        a3 = *(const bf16x8*)(bb + aBase + 3 * 2048 + sl0);
        b0 = *(const bf16x8*)(bb + bBase + 0 * 2048 + sl0);
        b1 = *(const bf16x8*)(bb + bBase + 1 * 2048 + sl0);
        b2 = *(const bf16x8*)(bb + bBase + 2 * 2048 + sl0);
        b3 = *(const bf16x8*)(bb + bBase + 3 * 2048 + sl0);
        MFMA16W();
        // kk1
        a0 = *(const bf16x8*)(bb + aBase + 0 * 2048 + sl1);
        a1 = *(const bf16x8*)(bb + aBase + 1 * 2048 + sl1);
        a2 = *(const bf16x8*)(bb + aBase + 2 * 2048 + sl1);
        a3 = *(const bf16x8*)(bb + aBase + 3 * 2048 + sl1);
        b0 = *(const bf16x8*)(bb + bBase + 0 * 2048 + sl1);
        b1 = *(const bf16x8*)(bb + bBase + 1 * 2048 + sl1);
        b2 = *(const bf16x8*)(bb + bBase + 2 * 2048 + sl1);
        b3 = *(const bf16x8*)(bb + bBase + 3 * 2048 + sl1);
        MFMA16W();

        if (t + 1 < T) {
            asm volatile("s_waitcnt vmcnt(0)" ::: "memory");
            __builtin_amdgcn_s_barrier();
            asm volatile("" ::: "memory");
        }
    }

    if (MODE == 0) {
        #pragma unroll
        for (int fm = 0; fm < 4; fm++)
            #pragma unroll
            for (int fn = 0; fn < 4; fn++)
                #pragma unroll
                for (int j = 0; j < 4; j++) {
                    int m = mbase + wrow * 64 + fm * 16 + hig * 4 + j;
                    int col = nbase + wcol * 64 + fn * 16 + ln15;
                    Cf[(size_t)m * N + col] = acc[fm][fn][j];
                }
    } else {
        const int colb = nbase + wcol * 64;
        const int sec = colb >> 11;               // 0=q, 1=k, 2=v
        if (sec < 2) {
            unsigned short* dst = (sec == 0) ? qp : kp;
            const float scale = (sec == 0) ? 0.08838834764831845f : 1.0f;
            #pragma unroll
            for (int fm = 0; fm < 4; fm++)
                #pragma unroll
                for (int fn = 0; fn < 4; fn++) {
                    int within = (colb & 2047) + fn * 16 + ln15;
                    int h = within >> 7, d = within & 127, pidx = d >> 1;
                    #pragma unroll
                    for (int j = 0; j < 4; j++) {
                        int m = mbase + wrow * 64 + fm * 16 + hig * 4 + j;
                        int b = m >> 11, tq = m & 2047;
                        float v = acc[fm][fn][j];
                        float pv = __shfl_xor(v, 1);
                        float c = ropeC[tq * 64 + pidx], s = ropeS[tq * 64 + pidx];
                        float o = (d & 1) ? fmaf(pv, s, v * c) : fmaf(-pv, s, v * c);
                        o *= scale;
                        dst[((size_t)((b << 4) + h) * 2048 + tq) * 128 + d] = f2bf(o);
                    }
                }
        } else {
            #pragma unroll
            for (int fm = 0; fm < 4; fm++)
                #pragma unroll
                for (int fn = 0; fn < 4; fn++) {
                    int within = (colb & 2047) + fn * 16 + ln15;
                    int h = within >> 7, d = within & 127;
                    int m0 = mbase + wrow * 64 + fm * 16 + hig * 4;
                    int b = m0 >> 11, t0 = m0 & 2047;
                    us4 pk = { f2bf(acc[fm][fn][0]), f2bf(acc[fm][fn][1]),
                               f2bf(acc[fm][fn][2]), f2bf(acc[fm][fn][3]) };
                    *(us4*)(vTp + ((size_t)((b << 4) + h) * 128 + d) * 2048 + t0) = pk;
                }
        }
    }
}

// ---------- flash attention (R10 proven): causal, swapped QK^T, KVBLK=64, dbuf, counted vmcnt ----------
// grid: (64, 8)  x = bh (XCD locality), y = q-pair.  q,k: [BH][T][D] (q pre-scaled); vT: [BH][D][T]
__global__ __launch_bounds__(256, 2) void attn_fwd(
    const unsigned short* __restrict__ q, const unsigned short* __restrict__ k,
    const unsigned short* __restrict__ vT, unsigned short* __restrict__ outp)
{
    __shared__ unsigned short lK[2][64 * 128];   // 2 x 16 KB, [kv][d], XOR-swizzled rows (256B)
    __shared__ unsigned short lV[2][128 * 64];   // 2 x 16 KB, [d][kv], XOR-swizzled rows (128B)
    __shared__ unsigned short lP[4 * 32 * 64];   // 16 KB, per-wave
    const int tid = threadIdx.x;
    const int lane = tid & 63, wid = tid >> 6;
    const int ln15 = lane & 15, hig = lane >> 4, hi8 = hig * 8;
    const int bh = blockIdx.x;

    const char* qg = (const char*)(q + (size_t)bh * 2048 * 128);
    const char* kg = (const char*)(k + (size_t)bh * 2048 * 128);
    const char* vg = (const char*)(vT + (size_t)bh * 128 * 2048);
    char* lKc = (char*)&lK[0][0];
    char* lVc = (char*)&lV[0][0];
    char* lPc = (char*)lP + wid * (32 * 64 * 2);
    const int b = bh >> 4, h = bh & 15;

    for (int rep = 0; rep < 2; rep++) {
        const int qt = rep == 0 ? (int)blockIdx.y : 15 - (int)blockIdx.y;
        const int qbase = qt * 128;
        const int qw = qbase + wid * 32;

        bf16x8 qf[2][4];
        #pragma unroll
        for (int mt = 0; mt < 2; mt++)
            #pragma unroll
            for (int ks = 0; ks < 4; ks++)
                qf[mt][ks] = *(const bf16x8*)(qg + ((size_t)(qw + mt * 16 + ln15) * 128 + ks * 32 + hi8) * 2);

        f32x4 o[2][8] = {};
        float mreg[2] = { -1e30f, -1e30f };
        float lreg[2] = { 0.f, 0.f };

        auto stageKV = [&](int bf, int kv0) {
            #pragma unroll
            for (int i = 0; i < 4; i++) {
                int slot = tid + i * 256;
                int row = slot >> 4, c = (slot & 15) * 16;
                gload16(kg + (size_t)(kv0 + row) * 256 + (c ^ ((row & 7) << 4)),
                        lKc + bf * 16384 + slot * 16);
            }
            #pragma unroll
            for (int i = 0; i < 4; i++) {
                int slot = tid + i * 256;
                int d = slot >> 3, c = (slot & 7) * 16;
                gload16(vg + (size_t)d * 4096 + (size_t)kv0 * 2 + (c ^ ((d & 7) << 4)),
                        lVc + bf * 16384 + slot * 16);
            }
        };

        const int ntiles = (qbase >> 6) + 2;   // >= 2 always
        stageKV(0, 0);
        if (ntiles > 1) stageKV(1, 64);

        for (int it = 0; it < ntiles; it++) {
            const int kv0 = it * 64;
            const int buf = it & 1;
            if (it + 1 < ntiles) asm volatile("s_waitcnt vmcnt(8)" ::: "memory");
            else                 asm volatile("s_waitcnt vmcnt(0)" ::: "memory");
            __builtin_amdgcn_s_barrier();

            if (kv0 <= qw + 31) {   // wave-active (causal range)
                const char* lKb = lKc + buf * 16384;
                const char* lVb = lVc + buf * 16384;

                f32x4 s[2][4] = {};
                #pragma unroll
                for (int ks = 0; ks < 4; ks++) {
                    bf16x8 kf[4];
                    #pragma unroll
                    for (int nt = 0; nt < 4; nt++) {
                        int row = nt * 16 + ln15;
                        kf[nt] = *(const bf16x8*)(lKb + row * 256 + (((ks * 32 + hi8) * 2) ^ ((row & 7) << 4)));
                    }
                    __builtin_amdgcn_s_setprio(1);
                    #pragma unroll
                    for (int mt = 0; mt < 2; mt++)
                        #pragma unroll
                        for (int nt = 0; nt < 4; nt++)
                            s[mt][nt] = __builtin_amdgcn_mfma_f32_16x16x32_bf16(kf[nt], qf[mt][ks], s[mt][nt], 0, 0, 0);
                    __builtin_amdgcn_s_setprio(0);
                }

                if (kv0 + 63 > qw) {  // diagonal tile: mask kv > q
                    #pragma unroll
                    for (int mt = 0; mt < 2; mt++) {
                        int qi = qw + mt * 16 + ln15;
                        #pragma unroll
                        for (int nt = 0; nt < 4; nt++)
                            #pragma unroll
                            for (int j = 0; j < 4; j++) {
                                int kvi = kv0 + nt * 16 + 4 * hig + j;
                                if (kvi > qi) s[mt][nt][j] = -1e30f;
                            }
                    }
                }

                float vmax[2];
                #pragma unroll
                for (int mt = 0; mt < 2; mt++) {
                    float v = fmaxf(fmaxf(s[mt][0][0], s[mt][0][1]), fmaxf(s[mt][0][2], s[mt][0][3]));
                    #pragma unroll
                    for (int nt = 1; nt < 4; nt++)
                        v = fmaxf(v, fmaxf(fmaxf(s[mt][nt][0], s[mt][nt][1]), fmaxf(s[mt][nt][2], s[mt][nt][3])));
                    v = fmaxf(v, __shfl_xor(v, 16));
                    v = fmaxf(v, __shfl_xor(v, 32));
                    vmax[mt] = v;
                }
                bool grow = (vmax[0] > mreg[0] + 8.0f) || (vmax[1] > mreg[1] + 8.0f);
                if (__any(grow)) {
                    float sc[2];
                    #pragma unroll
                    for (int mt = 0; mt < 2; mt++) {
                        float mn = fmaxf(mreg[mt], vmax[mt]);
                        sc[mt] = __expf(mreg[mt] - mn);
                        mreg[mt] = mn;
                        lreg[mt] *= sc[mt];
                    }
                    #pragma unroll
                    for (int mt = 0; mt < 2; mt++)
                        #pragma unroll
                        for (int j = 0; j < 4; j++) {
                            float scj = __shfl(sc[mt], 4 * hig + j);
                            #pragma unroll
                            for (int ntd = 0; ntd < 8; ntd++) o[mt][ntd][j] *= scj;
                        }
                }
                #pragma unroll
                for (int mt = 0; mt < 2; mt++) {
                    float rs = 0.f;
                    #pragma unroll
                    for (int nt = 0; nt < 4; nt++)
                        #pragma unroll
                        for (int j = 0; j < 4; j++) {
                            float p = __expf(s[mt][nt][j] - mreg[mt]);
                            s[mt][nt][j] = p;
                            rs += p;
                        }
                    rs += __shfl_xor(rs, 16);
                    rs += __shfl_xor(rs, 32);
                    lreg[mt] += rs;
                }

                #pragma unroll
                for (int mt = 0; mt < 2; mt++) {
                    int rr = mt * 16 + ln15;
                    int rx = (rr & 7) << 4;
                    #pragma unroll
                    for (int nt = 0; nt < 4; nt++) {
                        us4 pk = { f2bf(s[mt][nt][0]), f2bf(s[mt][nt][1]),
                                   f2bf(s[mt][nt][2]), f2bf(s[mt][nt][3]) };
                        int addr = rr * 128 + ((nt * 32 + hig * 8) ^ rx);
                        *(us4*)(lPc + addr) = pk;
                    }
                }

                #pragma unroll
                for (int ks2 = 0; ks2 < 2; ks2++) {
                    bf16x8 pf[2];
                    #pragma unroll
                    for (int mt = 0; mt < 2; mt++) {
                        int row = mt * 16 + ln15;
                        pf[mt] = *(const bf16x8*)(lPc + row * 128 + (((ks2 * 32 + hi8) * 2) ^ ((row & 7) << 4)));
                    }
                    #pragma unroll
                    for (int ntd = 0; ntd < 8; ntd++) {
                        int drow = ntd * 16 + ln15;
                        bf16x8 vf = *(const bf16x8*)(lVb + drow * 128 + (((ks2 * 32 + hi8) * 2) ^ ((drow & 7) << 4)));
                        __builtin_amdgcn_s_setprio(1);
                        #pragma unroll
                        for (int mt = 0; mt < 2; mt++)
                            o[mt][ntd] = __builtin_amdgcn_mfma_f32_16x16x32_bf16(pf[mt], vf, o[mt][ntd], 0, 0, 0);
                        __builtin_amdgcn_s_setprio(0);
                    }
                }
            }

            __builtin_amdgcn_s_barrier();
            if (it + 2 < ntiles) stageKV(buf, kv0 + 128);
        }

        #pragma unroll
        for (int mt = 0; mt < 2; mt++)
            #pragma unroll
            for (int j = 0; j < 4; j++) {
                float inv = 1.0f / __shfl(lreg[mt], 4 * hig + j);
                int t = qw + mt * 16 + hig * 4 + j;
                #pragma unroll
                for (int ntd = 0; ntd < 8; ntd++) {
                    int d = ntd * 16 + ln15;
                    outp[((size_t)b * 2048 + t) * 2048 + h * 128 + d] = f2bf(o[mt][ntd][j] * inv);
                }
            }
    }
}

// ---------- launcher ----------
extern "C" void kernel_launch(void* const* d_in, const int* in_sizes, int n_in,
                              void* d_out, int out_size, void* d_ws, size_t ws_size,
                              hipStream_t stream) {
    const float* x     = (const float*)d_in[0];
    const float* wqkv  = (const float*)d_in[1];
    const float* wo    = (const float*)d_in[2];
    const float* ropeC = (const float*)d_in[3];
    const float* ropeS = (const float*)d_in[4];
    float* out = (float*)d_out;
    char* ws = (char*)d_ws;
    const size_t MB = 1024 * 1024;
    unsigned short* xb    = (unsigned short*)(ws);                  // 32 MB
    unsigned short* wqkvT = (unsigned short*)(ws + 32 * MB);        // 24 MB
    unsigned short* woT   = (unsigned short*)(ws + 56 * MB);        // 8 MB
    unsigned short* qb    = (unsigned short*)(ws + 64 * MB);        // 32 MB
    unsigned short* kb    = (unsigned short*)(ws + 96 * MB);        // 32 MB
    unsigned short* vTb   = (unsigned short*)(ws + 128 * MB);       // 32 MB
    unsigned short* attnb = (unsigned short*)(ws + 160 * MB);       // 32 MB

    cvt_f32_bf16<<<2048, 256, 0, stream>>>(x, xb, 4194304);
    tcvt<<<dim3(96, 64), 256, 0, stream>>>(wqkv, wqkvT, 2048, 6144);
    tcvt<<<dim3(32, 64), 256, 0, stream>>>(wo, woT, 2048, 2048);
    gemmw<1><<<dim3(24, 32), 1024, 0, stream>>>(xb, wqkvT, 8192, 6144, 2048,
                                                nullptr, qb, kb, vTb, ropeC, ropeS, 8, 12);
    attn_fwd<<<dim3(64, 8), 256, 0, stream>>>(qb, kb, vTb, attnb);
    gemmw<0><<<dim3(8, 32), 1024, 0, stream>>>(attnb, woT, 8192, 2048, 2048,
                                               out, nullptr, nullptr, nullptr, nullptr, nullptr, 4, 8);
}